// Round 1
// baseline (914.767 us; speedup 1.0000x reference)
//
#include <hip/hip_runtime.h>
#include <math.h>

#define B_  64
#define N_  1024
#define H_  64
#define IN_ 512
#define G4  256   // 4*H

// ---------------------------------------------------------------------------
// Kernel A: xg[m][g] = sum_k x_row(m)[k] * W_ih[g][k] + b_ih[g] + b_hh[g]
// where m = n*64 + b, x_row(m) = x[b][n][:]  (x is [B][N][T*F] row-major)
// Tile 64(m) x 64(g), BK=32, 256 threads, 4x4 microtile per thread.
// ---------------------------------------------------------------------------
__global__ __launch_bounds__(256) void gemm_xg_kernel(
    const float* __restrict__ x,
    const float* __restrict__ Wih,
    const float* __restrict__ bih,
    const float* __restrict__ bhh,
    float* __restrict__ xg)
{
    // +4 pad: keeps float4 (16B) alignment per row, breaks staging-write
    // bank conflicts (8-way -> 4-way) and read conflicts.
    __shared__ float As[32][68];   // [k][m_local]
    __shared__ float Bs[32][68];   // [k][g_local]

    const int tid = threadIdx.x;
    const int g0  = blockIdx.x * 64;   // 4 g-tiles
    const int m0  = blockIdx.y * 64;   // 1024 m-tiles

    const int tx = tid & 15;           // g microtile index
    const int ty = tid >> 4;           // m microtile index

    // A staging: thread -> (row = tid/8 [+32], k-quad = tid%8)
    const int arow = tid >> 3;         // 0..31
    const int ak4  = tid & 7;          // 0..7
    // B staging: thread -> (g = tid/4, k-quad = tid%4 [+4])
    const int brow = tid >> 2;         // 0..63
    const int bk4  = tid & 3;          // 0..3

    float acc[4][4] = {{0.f}};

    for (int k0 = 0; k0 < IN_; k0 += 32) {
        #pragma unroll
        for (int half = 0; half < 2; ++half) {
            const int ml = arow + half * 32;
            const int m  = m0 + ml;
            const int bb = m & 63;     // batch index
            const int nn = m >> 6;     // node index
            const float4 v = *(const float4*)&x[((size_t)(bb * N_ + nn)) * IN_ + k0 + ak4 * 4];
            As[ak4 * 4 + 0][ml] = v.x;
            As[ak4 * 4 + 1][ml] = v.y;
            As[ak4 * 4 + 2][ml] = v.z;
            As[ak4 * 4 + 3][ml] = v.w;
        }
        #pragma unroll
        for (int half = 0; half < 2; ++half) {
            const int kq = bk4 + half * 4;   // 0..7
            const float4 v = *(const float4*)&Wih[(size_t)(g0 + brow) * IN_ + k0 + kq * 4];
            Bs[kq * 4 + 0][brow] = v.x;
            Bs[kq * 4 + 1][brow] = v.y;
            Bs[kq * 4 + 2][brow] = v.z;
            Bs[kq * 4 + 3][brow] = v.w;
        }
        __syncthreads();

        #pragma unroll
        for (int k = 0; k < 32; ++k) {
            const float4 av = *(const float4*)&As[k][ty * 4];
            const float4 bv = *(const float4*)&Bs[k][tx * 4];
            const float ar[4] = {av.x, av.y, av.z, av.w};
            const float br[4] = {bv.x, bv.y, bv.z, bv.w};
            #pragma unroll
            for (int i = 0; i < 4; ++i)
                #pragma unroll
                for (int j = 0; j < 4; ++j)
                    acc[i][j] = fmaf(ar[i], br[j], acc[i][j]);
        }
        __syncthreads();
    }

    float bias[4];
    #pragma unroll
    for (int j = 0; j < 4; ++j)
        bias[j] = bih[g0 + tx * 4 + j] + bhh[g0 + tx * 4 + j];

    #pragma unroll
    for (int i = 0; i < 4; ++i) {
        const int m = m0 + ty * 4 + i;
        float4 o;
        o.x = acc[i][0] + bias[0];
        o.y = acc[i][1] + bias[1];
        o.z = acc[i][2] + bias[2];
        o.w = acc[i][3] + bias[3];
        *(float4*)&xg[(size_t)m * G4 + g0 + tx * 4] = o;
    }
}

// ---------------------------------------------------------------------------
// Kernel B: recurrent LSTM scan. One block per batch row (64 blocks).
// Thread t (0..255) owns gate t; W_hh row t lives in 64 VGPRs.
// Gate groups [i|f|g|o] align exactly with waves 0..3 (no divergence).
// h (64 floats) round-trips through LDS; 2 barriers per step.
// ---------------------------------------------------------------------------
__global__ __launch_bounds__(256) void lstm_scan_kernel(
    const float* __restrict__ xg,    // [N][B][256]
    const float* __restrict__ Whh,   // [256][64]
    float* __restrict__ out)         // [B][N][64]
{
    const int t  = threadIdx.x;
    const int bb = blockIdx.x;

    __shared__ float h_sh[64];
    __shared__ float gate_sh[256];

    // W_hh row t -> registers (16 float4 = 64 VGPRs)
    float4 w4[16];
    #pragma unroll
    for (int q = 0; q < 16; ++q)
        w4[q] = *(const float4*)&Whh[(size_t)t * H_ + q * 4];

    float c = 0.f;                   // cell state (owned by threads t < 64)
    if (t < 64) h_sh[t] = 0.f;
    __syncthreads();

    float xg_cur = xg[(size_t)bb * G4 + t];   // n = 0

    for (int n = 0; n < N_; ++n) {
        // prefetch next step's xg (hides L3 latency behind the dot product)
        const int n1 = (n + 1 < N_) ? (n + 1) : (N_ - 1);
        const float xg_next = xg[((size_t)n1 * B_ + bb) * G4 + t];

        // gate pre-activation: xg + W_hh[t] . h
        float acc = xg_cur;
        #pragma unroll
        for (int q = 0; q < 16; ++q) {
            const float4 hv = *(const float4*)&h_sh[q * 4];   // broadcast reads
            acc = fmaf(w4[q].x, hv.x, acc);
            acc = fmaf(w4[q].y, hv.y, acc);
            acc = fmaf(w4[q].z, hv.z, acc);
            acc = fmaf(w4[q].w, hv.w, acc);
        }

        // activation (wave-uniform branch: waves 0,1,3 sigmoid; wave 2 tanh)
        float v;
        if (t < 128 || t >= 192) {
            v = 1.f / (1.f + __expf(-acc));            // sigmoid
        } else {
            v = 1.f - 2.f / (1.f + __expf(2.f * acc)); // tanh
        }

        gate_sh[t] = v;
        __syncthreads();   // barrier 1: gates visible; also fences h_sh reads

        if (t < 64) {
            const float gi = gate_sh[t];
            const float gf = gate_sh[64 + t];
            const float gg = gate_sh[128 + t];
            const float go = gate_sh[192 + t];
            c = fmaf(gf, c, gi * gg);
            const float th = 1.f - 2.f / (1.f + __expf(2.f * c)); // tanh(c)
            const float h  = go * th;
            h_sh[t] = h;
            out[((size_t)bb * N_ + n) * H_ + t] = h;
        }
        __syncthreads();   // barrier 2: new h visible to all waves

        xg_cur = xg_next;
    }
}

extern "C" void kernel_launch(void* const* d_in, const int* in_sizes, int n_in,
                              void* d_out, int out_size, void* d_ws, size_t ws_size,
                              hipStream_t stream)
{
    const float* x   = (const float*)d_in[0];
    const float* Wih = (const float*)d_in[1];
    const float* Whh = (const float*)d_in[2];
    const float* bih = (const float*)d_in[3];
    const float* bhh = (const float*)d_in[4];
    float* out = (float*)d_out;
    float* xg  = (float*)d_ws;   // 65536 * 256 * 4 B = 64 MiB scratch

    dim3 ggrid(4, 1024);   // (g-tiles, m-tiles)
    gemm_xg_kernel<<<ggrid, 256, 0, stream>>>(x, Wih, bih, bhh, xg);
    lstm_scan_kernel<<<64, 256, 0, stream>>>(xg, Whh, out);
}